// Round 8
// baseline (286.256 us; speedup 1.0000x reference)
//
#include <hip/hip_runtime.h>
#include <stdint.h>
#include <stddef.h>

#define N_TOK 16384
#define DM    1024
#define DFF   4096
#define NT    4
#define TU    1024   // d_ff tile
#define TD    256    // d_model tile

typedef __attribute__((ext_vector_type(8))) short  short8;
typedef __attribute__((ext_vector_type(4))) short  short4v;
typedef __attribute__((ext_vector_type(4))) float  floatx4;

__device__ inline unsigned short f2bf(float f){
  union { float f; uint32_t u; } v; v.f = f;
  uint32_t u = v.u + 0x7FFFu + ((v.u >> 16) & 1u);   // RNE
  return (unsigned short)(u >> 16);
}

// async global->LDS, 16B per lane; lds dest is wave-uniform, lane i lands at +16*i
__device__ __forceinline__ void gll16(const void* g, void* l){
  __builtin_amdgcn_global_load_lds(
      (const __attribute__((address_space(1))) unsigned int*)g,
      (__attribute__((address_space(3))) unsigned int*)l,
      16, 0, 0);
}

// ---------------- fused prep: sig partial sums + w_up->bf16 | w_down->bf16 --
// Blocks [0,256) do sig_partial work; blocks [256,2304) do wdown_conv work.
__global__ void k_prep(const float* __restrict__ w_up,
                       const float* __restrict__ w_down,
                       float* __restrict__ partial,
                       unsigned short* __restrict__ wupb,
                       unsigned short* __restrict__ wdownb){
  const int tid = threadIdx.x;
  if (blockIdx.x >= 256){
    const size_t i = ((size_t)(blockIdx.x - 256) * 256 + tid) * 8;
    floatx4 v0 = *(const floatx4*)(w_down + i);
    floatx4 v1 = *(const floatx4*)(w_down + i + 4);
    short8 p;
    p[0]=(short)f2bf(v0[0]); p[1]=(short)f2bf(v0[1]); p[2]=(short)f2bf(v0[2]); p[3]=(short)f2bf(v0[3]);
    p[4]=(short)f2bf(v1[0]); p[5]=(short)f2bf(v1[1]); p[6]=(short)f2bf(v1[2]); p[7]=(short)f2bf(v1[3]);
    *(short8*)(wdownb + i) = p;
    return;
  }
  const int b = blockIdx.x;
  const int tile = b >> 6, chunk = b & 63;
  const int c0 = tid * 4;
  const int row0 = tile*TU + chunk*16;
  float s0=0.f, s1=0.f, s2=0.f, s3=0.f;
  const float* base = w_up + (size_t)row0 * DM + c0;
  #pragma unroll
  for (int r = 0; r < 16; ++r){
    floatx4 v = *(const floatx4*)(base + (size_t)r * DM);
    s0 += v[0]; s1 += v[1]; s2 += v[2]; s3 += v[3];
    short4v p;
    p[0]=(short)f2bf(v[0]); p[1]=(short)f2bf(v[1]);
    p[2]=(short)f2bf(v[2]); p[3]=(short)f2bf(v[3]);
    *(short4v*)(wupb + (size_t)(row0 + r) * DM + c0) = p;
  }
  float* p = partial + ((size_t)tile*DM + c0) * 64 + chunk;
  p[0] = s0; p[64] = s1; p[128] = s2; p[192] = s3;
}

// ---------------- sig finalize ----------------------------------------------
__global__ void k_sig_final(const float* __restrict__ partial,
                            float* __restrict__ sig){
  const int g = blockIdx.x * 256 + threadIdx.x;   // 0..4095 = tile*1024+col
  const float* p = partial + (size_t)g * 64;
  float s = 0.f;
  #pragma unroll
  for (int i = 0; i < 64; ++i) s += p[i];
  sig[g] = (s > 0.f) ? 1.f : ((s < 0.f) ? -1.f : 0.f);
}

// ---------------- routing: fp64 scores + x->bf16 emit -----------------------
// 16 tokens/block (4 per wave); sig hoisted to registers. fp64 sum order
// UNCHANGED (u asc, j asc, shfl tree) -> winner bit-identical.
// xbf row n lives in SECOND 2048B of out row n (ushort offset n*2048+1024).
__global__ __launch_bounds__(256) void k_route(
    const float* __restrict__ x, const float* __restrict__ sig,
    float* __restrict__ gate_out, int* __restrict__ winner,
    unsigned short* __restrict__ xbf){
  __shared__ float ssig[NT * DM];
  const int tid = threadIdx.x;
  for (int i = tid; i < NT*DM; i += 256) ssig[i] = sig[i];
  __syncthreads();
  const int wv = tid >> 6, lane = tid & 63;

  floatx4 sg[4][4];
  #pragma unroll
  for (int j = 0; j < 4; ++j){
    const int c = j*256 + lane*4;
    #pragma unroll
    for (int tt = 0; tt < 4; ++tt)
      sg[j][tt] = *(const floatx4*)(ssig + tt*DM + c);
  }

  #pragma unroll
  for (int t = 0; t < 4; ++t){
    const int n = blockIdx.x * 16 + wv * 4 + t;
    const float* xr = x + (size_t)n * DM;
    unsigned short* xb = xbf + (size_t)n * 2048 + 1024;
    double a0=0.0, a1=0.0, a2=0.0, a3=0.0;
    #pragma unroll
    for (int j = 0; j < 4; ++j){
      const int c = j*256 + lane*4;
      floatx4 v = *(const floatx4*)(xr + c);
      short4v p;
      p[0]=(short)f2bf(v[0]); p[1]=(short)f2bf(v[1]);
      p[2]=(short)f2bf(v[2]); p[3]=(short)f2bf(v[3]);
      *(short4v*)(xb + c) = p;
      #pragma unroll
      for (int u = 0; u < 4; ++u){
        double xv = (double)v[u];
        a0 += xv * (double)sg[j][0][u];
        a1 += xv * (double)sg[j][1][u];
        a2 += xv * (double)sg[j][2][u];
        a3 += xv * (double)sg[j][3][u];
      }
    }
    #pragma unroll
    for (int off = 32; off > 0; off >>= 1){
      a0 += __shfl_down(a0, off, 64);
      a1 += __shfl_down(a1, off, 64);
      a2 += __shfl_down(a2, off, 64);
      a3 += __shfl_down(a3, off, 64);
    }
    if (lane == 0){
      double s[4] = {a0, a1, a2, a3};
      int w = 0;
      #pragma unroll
      for (int tt = 1; tt < 4; ++tt) if (s[tt] > s[w]) w = tt;   // first-max tiebreak
      floatx4 g = { w==0 ? 1.f:0.f, w==1 ? 1.f:0.f, w==2 ? 1.f:0.f, w==3 ? 1.f:0.f };
      *(floatx4*)(gate_out + (size_t)n * 4) = g;
      winner[n] = w;
    }
  }
}

// ---------------- fused sort: hist + scan + scatter, one block --------------
// R8: replaces 3 kernels (saves 2 launches + gaps) while keeping the idx
// ordering BIT-IDENTICAL to the old chain: segment <-> old hist/scatter
// block, sub-iter s <-> old wave index, scan walk identical (seg asc, t asc).
// Deterministic (R6 lesson: atomic-order idx cost gemm1 ~4us A-locality).
__global__ __launch_bounds__(256) void k_sort(const int* __restrict__ winner,
                                              int* __restrict__ meta,
                                              int* __restrict__ idx){
  __shared__ int cnt_s[64][NT];
  __shared__ int base_s[64][NT];
  const int tid = threadIdx.x, wv = tid >> 6, lane = tid & 63;

  // pass 1: per-segment counts (wave wv handles segments wv, wv+4, ...)
  for (int seg = wv; seg < 64; seg += 4){
    int c0 = 0, c1 = 0, c2 = 0, c3 = 0;
    #pragma unroll
    for (int s = 0; s < 4; ++s){
      const int w = winner[seg*256 + s*64 + lane];
      unsigned long long m0 = __ballot(w == 0);
      unsigned long long m1 = __ballot(w == 1);
      unsigned long long m2 = __ballot(w == 2);
      unsigned long long m3 = __ballot(w == 3);
      if (lane == 0){
        c0 += __popcll(m0); c1 += __popcll(m1);
        c2 += __popcll(m2); c3 += __popcll(m3);
      }
    }
    if (lane == 0){
      cnt_s[seg][0] = c0; cnt_s[seg][1] = c1;
      cnt_s[seg][2] = c2; cnt_s[seg][3] = c3;
    }
  }
  __syncthreads();

  if (tid == 0){
    int tot[NT] = {0,0,0,0};
    for (int b = 0; b < 64; ++b)
      for (int t = 0; t < NT; ++t) tot[t] += cnt_s[b][t];
    int off = 0, base[NT];
    for (int t = 0; t < NT; ++t){ meta[t] = tot[t]; meta[4+t] = off; base[t] = off; off += tot[t]; }
    for (int b = 0; b < 64; ++b)
      for (int t = 0; t < NT; ++t){ base_s[b][t] = base[t]; base[t] += cnt_s[b][t]; }
  }
  __syncthreads();

  // pass 2: scatter (same assignment; static-indexed running counts, rule #20)
  for (int seg = wv; seg < 64; seg += 4){
    int r0 = 0, r1 = 0, r2 = 0, r3 = 0;
    #pragma unroll
    for (int s = 0; s < 4; ++s){
      const int n = seg*256 + s*64 + lane;
      const int w = winner[n];
      unsigned long long m0 = __ballot(w == 0);
      unsigned long long m1 = __ballot(w == 1);
      unsigned long long m2 = __ballot(w == 2);
      unsigned long long m3 = __ballot(w == 3);
      unsigned long long mymask = (w == 0) ? m0 : (w == 1) ? m1 : (w == 2) ? m2 : m3;
      const int runw = (w == 0) ? r0 : (w == 1) ? r1 : (w == 2) ? r2 : r3;
      const unsigned long long below = (lane == 0) ? 0ull : (~0ull >> (64 - lane));
      idx[base_s[seg][w] + runw + __popcll(mymask & below)] = n;
      r0 += __popcll(m0); r1 += __popcll(m1);
      r2 += __popcll(m2); r3 += __popcll(m3);
    }
  }
}

// ---------------- GEMM1: hid = relu(xbf[rows] @ wupb[tile]^T + b_up) --------
// BM=128 BN=128; R0 body VERBATIM (structural pipeline variants R1-R3 all
// regressed; 33KB LDS -> 4 blk/CU TLP is the latency hiding).
// R8 swizzle refinement (R7's +15% win, pushed further): encode TILE into
// the XCD residue. id%8 = 2*tile + (chunk&1): each XCD serves exactly ONE
// tile -> its 2MB B panel is L2-RESIDENT for the XCD's whole lifetime
// (R7 map cycled all 4 tiles = 8MB > 4MB L2). The 8 nb-panels of one
// (tile,chunk) still share a residue (A chunk fetched once per L2, read 8x).
// Active chunks 0..~31 split even/odd -> all 8 residues stay busy.
__global__ __launch_bounds__(256, 2) void k_gemm1(
    const unsigned short* __restrict__ xbf,   // (ushort*)d_out; row n at n*2048+1024
    const unsigned short* __restrict__ wupb,  // [4096][1024] bf16
    const float* __restrict__ b_up, const int* __restrict__ meta,
    const int* __restrict__ idx, unsigned short* __restrict__ hid){
  // decode flat id: r=lin&7 -> (tile, chunk parity); q=lin>>3 -> (chunk half, nb)
  const int lin  = blockIdx.x;                 // [0,4096)
  const int r    = lin & 7, q = lin >> 3;
  const int tile = r >> 1;
  const int nb   = q & 7;
  const int chunk = ((q >> 3) << 1) | (r & 1); // [0,128)
  const int p0   = chunk * 128;

  const int cnt  = meta[tile];
  if (p0 >= cnt) return;
  const int off  = meta[4 + tile];

  __shared__ unsigned short smem[16384];  // As0|As1|Bs0|Bs1 (4096 ushorts each); epi overlays
  unsigned short* As0 = smem;
  unsigned short* As1 = smem + 4096;
  unsigned short* Bs0 = smem + 8192;
  unsigned short* Bs1 = smem + 12288;
  __shared__ int nrow[128];

  const int tid = threadIdx.x;
  if (tid < 128){
    int p = p0 + tid;
    nrow[tid] = idx[off + (p < cnt ? p : cnt - 1)];
  }
  __syncthreads();

  const int wv = tid >> 6, lane = tid & 63;
  const int wm = (wv >> 1) * 64, wn = (wv & 1) * 64;
  const int l16 = lane & 15, quad = lane >> 4;

  const int rsub = lane >> 2;          // 0..15
  const int kus  = (lane & 3) * 8;     // ushort offset within 32-elem row

  const int ra = wv*32 + rsub;
  const unsigned short* aptr0 = xbf + (size_t)nrow[ra]      * 2048 + 1024 + kus;
  const unsigned short* aptr1 = xbf + (size_t)nrow[ra + 16] * 2048 + 1024 + kus;
  const unsigned short* bptr0 = wupb + (size_t)(tile*TU + nb*128 + wv*32 + rsub) * DM + kus;
  const unsigned short* bptr1 = bptr0 + 16 * DM;

  // wave-uniform LDS dests ([row][32] layout, 64B row stride)
  unsigned short* a0d0 = As0 + (wv*32) * 32;  unsigned short* a0d1 = a0d0 + 16*32;
  unsigned short* a1d0 = As1 + (wv*32) * 32;  unsigned short* a1d1 = a1d0 + 16*32;
  unsigned short* b0d0 = Bs0 + (wv*32) * 32;  unsigned short* b0d1 = b0d0 + 16*32;
  unsigned short* b1d0 = Bs1 + (wv*32) * 32;  unsigned short* b1d1 = b1d0 + 16*32;

  floatx4 acc[4][4];
  #pragma unroll
  for (int i = 0; i < 4; ++i)
    #pragma unroll
    for (int j = 0; j < 4; ++j) acc[i][j] = (floatx4){0.f,0.f,0.f,0.f};

  for (int k0 = 0; k0 < DM; k0 += 64){
    gll16(aptr0 + k0,      a0d0);
    gll16(aptr1 + k0,      a0d1);
    gll16(aptr0 + k0 + 32, a1d0);
    gll16(aptr1 + k0 + 32, a1d1);
    gll16(bptr0 + k0,      b0d0);
    gll16(bptr1 + k0,      b0d1);
    gll16(bptr0 + k0 + 32, b1d0);
    gll16(bptr1 + k0 + 32, b1d1);
    __syncthreads();
    {
      short8 af[4], bfr[4];
      #pragma unroll
      for (int i = 0; i < 4; ++i) af[i]  = *(const short8*)(As0 + (wm + i*16 + l16)*32 + quad*8);
      #pragma unroll
      for (int j = 0; j < 4; ++j) bfr[j] = *(const short8*)(Bs0 + (wn + j*16 + l16)*32 + quad*8);
      #pragma unroll
      for (int i = 0; i < 4; ++i)
        #pragma unroll
        for (int j = 0; j < 4; ++j)
          acc[i][j] = __builtin_amdgcn_mfma_f32_16x16x32_bf16(af[i], bfr[j], acc[i][j], 0, 0, 0);
    }
    {
      short8 af[4], bfr[4];
      #pragma unroll
      for (int i = 0; i < 4; ++i) af[i]  = *(const short8*)(As1 + (wm + i*16 + l16)*32 + quad*8);
      #pragma unroll
      for (int j = 0; j < 4; ++j) bfr[j] = *(const short8*)(Bs1 + (wn + j*16 + l16)*32 + quad*8);
      #pragma unroll
      for (int i = 0; i < 4; ++i)
        #pragma unroll
        for (int j = 0; j < 4; ++j)
          acc[i][j] = __builtin_amdgcn_mfma_f32_16x16x32_bf16(af[i], bfr[j], acc[i][j], 0, 0, 0);
    }
    __syncthreads();
  }

  // epilogue: two half-passes of 64 rows through LDS (pad stride 136), wide stores
  const int gcol0 = nb*128;
  #pragma unroll
  for (int half = 0; half < 2; ++half){
    if ((wv >> 1) == half){
      #pragma unroll
      for (int i = 0; i < 4; ++i){
        #pragma unroll
        for (int j = 0; j < 4; ++j){
          const int col = wn + j*16 + l16;          // 0..127
          const float bias = b_up[tile*TU + gcol0 + col];
          #pragma unroll
          for (int r2 = 0; r2 < 4; ++r2){
            const int lrow = i*16 + quad*4 + r2;    // 0..63
            float v = acc[i][j][r2] + bias;
            smem[lrow*136 + col] = f2bf(v > 0.f ? v : 0.f);
          }
        }
      }
    }
    __syncthreads();
    // 64 rows x 16 chunks of 8 ushorts (128 cols)
    #pragma unroll
    for (int c = tid; c < 1024; c += 256){
      const int lrow = c >> 4, k8 = (c & 15) * 8;
      const int m = half*64 + lrow;
      if (p0 + m < cnt){
        short8 vv = *(const short8*)(smem + lrow*136 + k8);
        *(short8*)(hid + (size_t)nrow[m]*2048 + gcol0 + k8) = vv;
      }
    }
    __syncthreads();
  }
}

// ---------------- GEMM2: out = hid @ wdownb[tile]^T + b_down + zero-fill ----
// BM=32 BN=256, BK=64 paired buffers (R0 structure verbatim). R8: same
// tile-into-residue XCD swizzle (id%8 = 2*tile + (x&1)): each XCD serves one
// tile -> 512KB B panel L2-resident. Zero-fill fused after K-loop's final
// barrier (all hid reads drained; each token's hid read by exactly this block).
__global__ __launch_bounds__(256, 2) void k_gemm2(
    const unsigned short* __restrict__ hid,    // (ushort*)d_out; row n at n*2048
    const unsigned short* __restrict__ wdownb, // [1024][4096] bf16
    const float* __restrict__ b_down, const int* __restrict__ meta,
    const int* __restrict__ idx, float* __restrict__ out){
  const int lin  = blockIdx.x;                 // [0,2048)
  const int r    = lin & 7, q = lin >> 3;
  const int tile = r >> 1;
  const int xx   = (q << 1) | (r & 1);         // [0,512)
  const int p0   = xx * 32;

  const int cnt  = meta[tile];
  if (p0 >= cnt) return;
  const int off  = meta[4 + tile];

  __shared__ unsigned short smem[18432];  // As0|As1 (1024 each) | Bs0|Bs1 (8192 each)
  unsigned short* As0 = smem;
  unsigned short* As1 = smem + 1024;
  unsigned short* Bs0 = smem + 2048;
  unsigned short* Bs1 = smem + 10240;
  float* epi = (float*)smem;              // overlay: 16 rows x 260 floats = 16640B
  __shared__ int nrow[32];

  const int tid = threadIdx.x;
  if (tid < 32){
    int p = p0 + tid;
    nrow[tid] = idx[off + (p < cnt ? p : cnt - 1)];
  }
  __syncthreads();

  const int wv = tid >> 6, lane = tid & 63;
  const int wn = wv * 64;
  const int l16 = lane & 15, quad = lane >> 4;

  const int rsub = lane >> 2;
  const int kus  = (lane & 3) * 8;

  const int arow = (wv & 1)*16 + rsub;
  const unsigned short* aptr = hid + (size_t)nrow[arow] * 2048 + kus;
  const int aoff = (wv >> 1) * 32;                     // k-chunk offset
  unsigned short* asd = (wv < 2 ? As0 : As1) + ((wv & 1)*16) * 32;
  const unsigned short* bptr = wdownb + (size_t)(tile*TD + wv*64 + rsub) * DFF + tile*TU + kus;
  unsigned short* bsd0 = Bs0 + (wv*64) * 32;
  unsigned short* bsd1 = Bs1 + (wv*64) * 32;

  floatx4 acc[2][4];
  #pragma unroll
  for (int i = 0; i < 2; ++i)
    #pragma unroll
    for (int j = 0; j < 4; ++j) acc[i][j] = (floatx4){0.f,0.f,0.f,0.f};

  for (int k0 = 0; k0 < TU; k0 += 64){
    gll16(aptr + k0 + aoff, asd);
    gll16(bptr + k0,               bsd0);
    gll16(bptr + k0 + 16*DFF,      bsd0 + 16*32);
    gll16(bptr + k0 + 32*DFF,      bsd0 + 32*32);
    gll16(bptr + k0 + 48*DFF,      bsd0 + 48*32);
    gll16(bptr + k0 + 32,          bsd1);
    gll16(bptr + k0 + 32 + 16*DFF, bsd1 + 16*32);
    gll16(bptr + k0 + 32 + 32*DFF, bsd1 + 32*32);
    gll16(bptr + k0 + 32 + 48*DFF, bsd1 + 48*32);
    __syncthreads();
    {
      short8 af[2], bfr[4];
      #pragma unroll
      for (int i = 0; i < 2; ++i) af[i]  = *(const short8*)(As0 + (i*16 + l16)*32 + quad*8);
      #pragma unroll
      for (int j = 0; j < 4; ++j) bfr[j] = *(const short8*)(Bs0 + (wn + j*16 + l16)*32 + quad*8);
      #pragma unroll
      for (int i = 0; i < 2; ++i)
        #pragma unroll
        for (int j = 0; j < 4; ++j)
          acc[i][j] = __builtin_amdgcn_mfma_f32_16x16x32_bf16(af[i], bfr[j], acc[i][j], 0, 0, 0);
    }
    {
      short8 af[2], bfr[4];
      #pragma unroll
      for (int i = 0; i < 2; ++i) af[i]  = *(const short8*)(As1 + (i*16 + l16)*32 + quad*8);
      #pragma unroll
      for (int j = 0; j < 4; ++j) bfr[j] = *(const short8*)(Bs1 + (wn + j*16 + l16)*32 + quad*8);
      #pragma unroll
      for (int i = 0; i < 2; ++i)
        #pragma unroll
        for (int j = 0; j < 4; ++j)
          acc[i][j] = __builtin_amdgcn_mfma_f32_16x16x32_bf16(af[i], bfr[j], acc[i][j], 0, 0, 0);
    }
    __syncthreads();
  }

  // zero-fill non-winner 256-col blocks of OWN tokens (hid reads all drained)
  const floatx4 z4 = {0.f, 0.f, 0.f, 0.f};
  #pragma unroll
  for (int cb = 0; cb < 4; ++cb){
    if (cb == tile) continue;
    for (int c = tid; c < 32*64; c += 256){
      const int rowl = c >> 6, c4 = (c & 63) * 4;
      if (p0 + rowl < cnt)
        *(floatx4*)(out + (size_t)nrow[rowl]*DM + cb*256 + c4) = z4;
    }
  }

  // epilogue: two half-passes of 16 rows via LDS fp32 (pad stride 260), float4 stores
  #pragma unroll
  for (int half = 0; half < 2; ++half){
    #pragma unroll
    for (int j = 0; j < 4; ++j){
      const int col = wn + j*16 + l16;              // 0..255
      const float bias = b_down[tile*TD + col];
      #pragma unroll
      for (int r2 = 0; r2 < 4; ++r2){
        const int lrow = quad*4 + r2;               // 0..15
        epi[lrow*260 + col] = acc[half][j][r2] + bias;
      }
    }
    __syncthreads();
    #pragma unroll
    for (int c = tid; c < 1024; c += 256){          // 16 rows x 64 float4 chunks
      const int lrow = c >> 6, c4 = (c & 63) * 4;
      const int m = half*16 + lrow;
      if (p0 + m < cnt){
        floatx4 v = *(const floatx4*)(epi + lrow*260 + c4);
        *(floatx4*)(out + (size_t)nrow[m]*DM + tile*TD + c4) = v;
      }
    }
    __syncthreads();
  }
}

extern "C" void kernel_launch(void* const* d_in, const int* in_sizes, int n_in,
                              void* d_out, int out_size, void* d_ws, size_t ws_size,
                              hipStream_t stream){
  const float* x      = (const float*)d_in[0];
  const float* w_up   = (const float*)d_in[1];
  const float* b_up   = (const float*)d_in[2];
  const float* w_down = (const float*)d_in[3];
  const float* b_down = (const float*)d_in[4];

  // ws layout (~17.3 MB; proven layout)
  unsigned short* wupb   = (unsigned short*)d_ws;            // 4096*1024 bf16 = 8 MB
  unsigned short* wdownb = wupb + (size_t)DFF * DM;          // 1024*4096 bf16 = 8 MB
  float* partial = (float*)(wdownb + (size_t)DM * DFF);      // 262144 floats = 1 MB
  float* sig     = partial + 262144;                         // 4096 floats
  int*   ints    = (int*)(sig + 4096);
  int*   winner   = ints;                                    // 16384
  int*   idx      = ints + 16384;                            // 16384
  int*   meta     = ints + 32768;                            // [0..3]=counts [4..7]=offsets

  float*          out  = (float*)d_out;
  float*          gate = out + (size_t)N_TOK * DM;
  unsigned short* ob16 = (unsigned short*)d_out;  // row n: hid at n*2048, xbf at n*2048+1024

  k_prep      <<<dim3(2304), 256, 0, stream>>>(w_up, w_down, partial, wupb, wdownb);
  k_sig_final <<<dim3(16),   256, 0, stream>>>(partial, sig);
  k_route     <<<dim3(N_TOK/16), 256, 0, stream>>>(x, sig, gate, winner, ob16);
  k_sort      <<<dim3(1),    256, 0, stream>>>(winner, meta, idx);
  k_gemm1     <<<dim3(4096), 256, 0, stream>>>(ob16, wupb, b_up, meta, idx, ob16);
  k_gemm2     <<<dim3(2048), 256, 0, stream>>>(ob16, wdownb, b_down, meta, idx, out);
}

// Round 9
// 261.405 us; speedup vs baseline: 1.0951x; 1.0951x over previous
//
#include <hip/hip_runtime.h>
#include <stdint.h>
#include <stddef.h>

#define N_TOK 16384
#define DM    1024
#define DFF   4096
#define NT    4
#define TU    1024   // d_ff tile
#define TD    256    // d_model tile

typedef __attribute__((ext_vector_type(8))) short  short8;
typedef __attribute__((ext_vector_type(4))) short  short4v;
typedef __attribute__((ext_vector_type(4))) float  floatx4;

__device__ inline unsigned short f2bf(float f){
  union { float f; uint32_t u; } v; v.f = f;
  uint32_t u = v.u + 0x7FFFu + ((v.u >> 16) & 1u);   // RNE
  return (unsigned short)(u >> 16);
}

// async global->LDS, 16B per lane; lds dest is wave-uniform, lane i lands at +16*i
__device__ __forceinline__ void gll16(const void* g, void* l){
  __builtin_amdgcn_global_load_lds(
      (const __attribute__((address_space(1))) unsigned int*)g,
      (__attribute__((address_space(3))) unsigned int*)l,
      16, 0, 0);
}

// ---------------- fused prep: sig partial sums + w_up->bf16 | w_down->bf16 --
// Blocks [0,256) do sig_partial work; blocks [256,2304) do wdown_conv work.
__global__ void k_prep(const float* __restrict__ w_up,
                       const float* __restrict__ w_down,
                       float* __restrict__ partial,
                       unsigned short* __restrict__ wupb,
                       unsigned short* __restrict__ wdownb){
  const int tid = threadIdx.x;
  if (blockIdx.x >= 256){
    const size_t i = ((size_t)(blockIdx.x - 256) * 256 + tid) * 8;
    floatx4 v0 = *(const floatx4*)(w_down + i);
    floatx4 v1 = *(const floatx4*)(w_down + i + 4);
    short8 p;
    p[0]=(short)f2bf(v0[0]); p[1]=(short)f2bf(v0[1]); p[2]=(short)f2bf(v0[2]); p[3]=(short)f2bf(v0[3]);
    p[4]=(short)f2bf(v1[0]); p[5]=(short)f2bf(v1[1]); p[6]=(short)f2bf(v1[2]); p[7]=(short)f2bf(v1[3]);
    *(short8*)(wdownb + i) = p;
    return;
  }
  const int b = blockIdx.x;
  const int tile = b >> 6, chunk = b & 63;
  const int c0 = tid * 4;
  const int row0 = tile*TU + chunk*16;
  float s0=0.f, s1=0.f, s2=0.f, s3=0.f;
  const float* base = w_up + (size_t)row0 * DM + c0;
  #pragma unroll
  for (int r = 0; r < 16; ++r){
    floatx4 v = *(const floatx4*)(base + (size_t)r * DM);
    s0 += v[0]; s1 += v[1]; s2 += v[2]; s3 += v[3];
    short4v p;
    p[0]=(short)f2bf(v[0]); p[1]=(short)f2bf(v[1]);
    p[2]=(short)f2bf(v[2]); p[3]=(short)f2bf(v[3]);
    *(short4v*)(wupb + (size_t)(row0 + r) * DM + c0) = p;
  }
  float* p = partial + ((size_t)tile*DM + c0) * 64 + chunk;
  p[0] = s0; p[64] = s1; p[128] = s2; p[192] = s3;
}

// ---------------- sig finalize ----------------------------------------------
__global__ void k_sig_final(const float* __restrict__ partial,
                            float* __restrict__ sig){
  const int g = blockIdx.x * 256 + threadIdx.x;   // 0..4095 = tile*1024+col
  const float* p = partial + (size_t)g * 64;
  float s = 0.f;
  #pragma unroll
  for (int i = 0; i < 64; ++i) s += p[i];
  sig[g] = (s > 0.f) ? 1.f : ((s < 0.f) ? -1.f : 0.f);
}

// ---------------- routing: fp64 scores + x->bf16 emit -----------------------
// 16 tokens/block (4 per wave); sig hoisted to registers. fp64 sum order
// UNCHANGED (u asc, j asc, shfl tree) -> winner bit-identical.
// xbf row n lives in SECOND 2048B of out row n (ushort offset n*2048+1024).
__global__ __launch_bounds__(256) void k_route(
    const float* __restrict__ x, const float* __restrict__ sig,
    float* __restrict__ gate_out, int* __restrict__ winner,
    unsigned short* __restrict__ xbf){
  __shared__ float ssig[NT * DM];
  const int tid = threadIdx.x;
  for (int i = tid; i < NT*DM; i += 256) ssig[i] = sig[i];
  __syncthreads();
  const int wv = tid >> 6, lane = tid & 63;

  floatx4 sg[4][4];
  #pragma unroll
  for (int j = 0; j < 4; ++j){
    const int c = j*256 + lane*4;
    #pragma unroll
    for (int tt = 0; tt < 4; ++tt)
      sg[j][tt] = *(const floatx4*)(ssig + tt*DM + c);
  }

  #pragma unroll
  for (int t = 0; t < 4; ++t){
    const int n = blockIdx.x * 16 + wv * 4 + t;
    const float* xr = x + (size_t)n * DM;
    unsigned short* xb = xbf + (size_t)n * 2048 + 1024;
    double a0=0.0, a1=0.0, a2=0.0, a3=0.0;
    #pragma unroll
    for (int j = 0; j < 4; ++j){
      const int c = j*256 + lane*4;
      floatx4 v = *(const floatx4*)(xr + c);
      short4v p;
      p[0]=(short)f2bf(v[0]); p[1]=(short)f2bf(v[1]);
      p[2]=(short)f2bf(v[2]); p[3]=(short)f2bf(v[3]);
      *(short4v*)(xb + c) = p;
      #pragma unroll
      for (int u = 0; u < 4; ++u){
        double xv = (double)v[u];
        a0 += xv * (double)sg[j][0][u];
        a1 += xv * (double)sg[j][1][u];
        a2 += xv * (double)sg[j][2][u];
        a3 += xv * (double)sg[j][3][u];
      }
    }
    #pragma unroll
    for (int off = 32; off > 0; off >>= 1){
      a0 += __shfl_down(a0, off, 64);
      a1 += __shfl_down(a1, off, 64);
      a2 += __shfl_down(a2, off, 64);
      a3 += __shfl_down(a3, off, 64);
    }
    if (lane == 0){
      double s[4] = {a0, a1, a2, a3};
      int w = 0;
      #pragma unroll
      for (int tt = 1; tt < 4; ++tt) if (s[tt] > s[w]) w = tt;   // first-max tiebreak
      floatx4 g = { w==0 ? 1.f:0.f, w==1 ? 1.f:0.f, w==2 ? 1.f:0.f, w==3 ? 1.f:0.f };
      *(floatx4*)(gate_out + (size_t)n * 4) = g;
      winner[n] = w;
    }
  }
}

// ---------------- histogram / scan / scatter (atomic-free, deterministic) ---
// R9: REVERT of R8's single-block k_sort fusion (+20us: one block doing 128
// dependent global-read rounds = serial latency; the 64-block parallel chain
// is ~10us). Launch-count frugality loses when it serializes (R6 already
// showed launch overhead is not the elephant).
__global__ void k_hist(const int* __restrict__ winner,
                       int* __restrict__ blk_cnt){   // [64][4]
  __shared__ int wcnt[4][NT];
  const int tid = threadIdx.x, wv = tid >> 6, lane = tid & 63;
  const int w = winner[blockIdx.x * 256 + tid];
  #pragma unroll
  for (int t = 0; t < NT; ++t){
    unsigned long long m = __ballot(w == t);
    if (lane == 0) wcnt[wv][t] = __popcll(m);
  }
  __syncthreads();
  if (tid < NT){
    int s = wcnt[0][tid] + wcnt[1][tid] + wcnt[2][tid] + wcnt[3][tid];
    blk_cnt[blockIdx.x * NT + tid] = s;
  }
}

__global__ void k_scan(const int* __restrict__ blk_cnt,
                       int* __restrict__ meta, int* __restrict__ blk_base){
  __shared__ int s[256];
  const int tid = threadIdx.x;
  s[tid] = blk_cnt[tid];                    // one coalesced load
  __syncthreads();
  if (tid == 0){
    int tot[NT] = {0,0,0,0};
    for (int b = 0; b < 64; ++b)
      for (int t = 0; t < NT; ++t) tot[t] += s[b*NT + t];
    int off = 0, base[NT];
    for (int t = 0; t < NT; ++t){ meta[t] = tot[t]; meta[4+t] = off; base[t] = off; off += tot[t]; }
    for (int b = 0; b < 64; ++b)
      for (int t = 0; t < NT; ++t){ int c = s[b*NT + t]; s[b*NT + t] = base[t]; base[t] += c; }
  }
  __syncthreads();
  blk_base[tid] = s[tid];                   // parallel store
}

__global__ void k_scatter(const int* __restrict__ winner,
                          const int* __restrict__ blk_base,
                          int* __restrict__ idx){
  __shared__ int wcnt[4][NT];
  const int tid = threadIdx.x, wv = tid >> 6, lane = tid & 63;
  const int n = blockIdx.x * 256 + tid;
  const int w = winner[n];
  unsigned long long mymask = 0;
  #pragma unroll
  for (int t = 0; t < NT; ++t){
    unsigned long long m = __ballot(w == t);
    if (lane == 0) wcnt[wv][t] = __popcll(m);
    if (t == w) mymask = m;
  }
  __syncthreads();
  const unsigned long long below = (lane == 0) ? 0ull : (~0ull >> (64 - lane));
  int pos = blk_base[blockIdx.x * NT + w] + __popcll(mymask & below);
  for (int v = 0; v < wv; ++v) pos += wcnt[v][w];
  idx[pos] = n;
}

// ---------------- GEMM1: hid = relu(xbf[rows] @ wupb[tile]^T + b_up) --------
// BM=128 BN=128; R0 body VERBATIM (pipeline variants R1-R3 all regressed;
// 33KB LDS -> 4 blk/CU TLP is the latency hiding).
// Tile-into-residue XCD swizzle (R8, VALIDATED: FETCH 55->27MB, dur -1.5us):
// id%8 = 2*tile + (chunk&1) -> each XCD serves ONE tile; its 2MB B panel is
// L2-resident for the XCD's lifetime; the 8 nb-panels of one (tile,chunk)
// share a residue so the A chunk is fetched once per L2 and read 8x.
// gemm1 is now NOT BW-bound (FETCH near compulsory ideal); remaining 56us is
// the 2-barrier structure's concurrency floor. Next lever would be the full
// 8-phase counted-vmcnt rewrite — high risk, parked.
__global__ __launch_bounds__(256, 2) void k_gemm1(
    const unsigned short* __restrict__ xbf,   // (ushort*)d_out; row n at n*2048+1024
    const unsigned short* __restrict__ wupb,  // [4096][1024] bf16
    const float* __restrict__ b_up, const int* __restrict__ meta,
    const int* __restrict__ idx, unsigned short* __restrict__ hid){
  // decode flat id: r=lin&7 -> (tile, chunk parity); q=lin>>3 -> (nb, chunk half)
  const int lin  = blockIdx.x;                 // [0,4096)
  const int r    = lin & 7, q = lin >> 3;
  const int tile = r >> 1;
  const int nb   = q & 7;
  const int chunk = ((q >> 3) << 1) | (r & 1); // [0,128)
  const int p0   = chunk * 128;

  const int cnt  = meta[tile];
  if (p0 >= cnt) return;
  const int off  = meta[4 + tile];

  __shared__ unsigned short smem[16384];  // As0|As1|Bs0|Bs1 (4096 ushorts each); epi overlays
  unsigned short* As0 = smem;
  unsigned short* As1 = smem + 4096;
  unsigned short* Bs0 = smem + 8192;
  unsigned short* Bs1 = smem + 12288;
  __shared__ int nrow[128];

  const int tid = threadIdx.x;
  if (tid < 128){
    int p = p0 + tid;
    nrow[tid] = idx[off + (p < cnt ? p : cnt - 1)];
  }
  __syncthreads();

  const int wv = tid >> 6, lane = tid & 63;
  const int wm = (wv >> 1) * 64, wn = (wv & 1) * 64;
  const int l16 = lane & 15, quad = lane >> 4;

  const int rsub = lane >> 2;          // 0..15
  const int kus  = (lane & 3) * 8;     // ushort offset within 32-elem row

  const int ra = wv*32 + rsub;
  const unsigned short* aptr0 = xbf + (size_t)nrow[ra]      * 2048 + 1024 + kus;
  const unsigned short* aptr1 = xbf + (size_t)nrow[ra + 16] * 2048 + 1024 + kus;
  const unsigned short* bptr0 = wupb + (size_t)(tile*TU + nb*128 + wv*32 + rsub) * DM + kus;
  const unsigned short* bptr1 = bptr0 + 16 * DM;

  // wave-uniform LDS dests ([row][32] layout, 64B row stride)
  unsigned short* a0d0 = As0 + (wv*32) * 32;  unsigned short* a0d1 = a0d0 + 16*32;
  unsigned short* a1d0 = As1 + (wv*32) * 32;  unsigned short* a1d1 = a1d0 + 16*32;
  unsigned short* b0d0 = Bs0 + (wv*32) * 32;  unsigned short* b0d1 = b0d0 + 16*32;
  unsigned short* b1d0 = Bs1 + (wv*32) * 32;  unsigned short* b1d1 = b1d0 + 16*32;

  floatx4 acc[4][4];
  #pragma unroll
  for (int i = 0; i < 4; ++i)
    #pragma unroll
    for (int j = 0; j < 4; ++j) acc[i][j] = (floatx4){0.f,0.f,0.f,0.f};

  for (int k0 = 0; k0 < DM; k0 += 64){
    gll16(aptr0 + k0,      a0d0);
    gll16(aptr1 + k0,      a0d1);
    gll16(aptr0 + k0 + 32, a1d0);
    gll16(aptr1 + k0 + 32, a1d1);
    gll16(bptr0 + k0,      b0d0);
    gll16(bptr1 + k0,      b0d1);
    gll16(bptr0 + k0 + 32, b1d0);
    gll16(bptr1 + k0 + 32, b1d1);
    __syncthreads();
    {
      short8 af[4], bfr[4];
      #pragma unroll
      for (int i = 0; i < 4; ++i) af[i]  = *(const short8*)(As0 + (wm + i*16 + l16)*32 + quad*8);
      #pragma unroll
      for (int j = 0; j < 4; ++j) bfr[j] = *(const short8*)(Bs0 + (wn + j*16 + l16)*32 + quad*8);
      #pragma unroll
      for (int i = 0; i < 4; ++i)
        #pragma unroll
        for (int j = 0; j < 4; ++j)
          acc[i][j] = __builtin_amdgcn_mfma_f32_16x16x32_bf16(af[i], bfr[j], acc[i][j], 0, 0, 0);
    }
    {
      short8 af[4], bfr[4];
      #pragma unroll
      for (int i = 0; i < 4; ++i) af[i]  = *(const short8*)(As1 + (wm + i*16 + l16)*32 + quad*8);
      #pragma unroll
      for (int j = 0; j < 4; ++j) bfr[j] = *(const short8*)(Bs1 + (wn + j*16 + l16)*32 + quad*8);
      #pragma unroll
      for (int i = 0; i < 4; ++i)
        #pragma unroll
        for (int j = 0; j < 4; ++j)
          acc[i][j] = __builtin_amdgcn_mfma_f32_16x16x32_bf16(af[i], bfr[j], acc[i][j], 0, 0, 0);
    }
    __syncthreads();
  }

  // epilogue: two half-passes of 64 rows through LDS (pad stride 136), wide stores
  const int gcol0 = nb*128;
  #pragma unroll
  for (int half = 0; half < 2; ++half){
    if ((wv >> 1) == half){
      #pragma unroll
      for (int i = 0; i < 4; ++i){
        #pragma unroll
        for (int j = 0; j < 4; ++j){
          const int col = wn + j*16 + l16;          // 0..127
          const float bias = b_up[tile*TU + gcol0 + col];
          #pragma unroll
          for (int r2 = 0; r2 < 4; ++r2){
            const int lrow = i*16 + quad*4 + r2;    // 0..63
            float v = acc[i][j][r2] + bias;
            smem[lrow*136 + col] = f2bf(v > 0.f ? v : 0.f);
          }
        }
      }
    }
    __syncthreads();
    // 64 rows x 16 chunks of 8 ushorts (128 cols)
    #pragma unroll
    for (int c = tid; c < 1024; c += 256){
      const int lrow = c >> 4, k8 = (c & 15) * 8;
      const int m = half*64 + lrow;
      if (p0 + m < cnt){
        short8 vv = *(const short8*)(smem + lrow*136 + k8);
        *(short8*)(hid + (size_t)nrow[m]*2048 + gcol0 + k8) = vv;
      }
    }
    __syncthreads();
  }
}

// ---------------- GEMM2: out = hid @ wdownb[tile]^T + b_down + zero-fill ----
// BM=32 BN=256, BK=64 paired buffers (R0 structure verbatim). Tile-into-
// residue XCD swizzle (id%8 = 2*tile + (x&1)): each XCD serves one tile ->
// 512KB B panel L2-resident. Zero-fill fused after K-loop's final barrier.
__global__ __launch_bounds__(256, 2) void k_gemm2(
    const unsigned short* __restrict__ hid,    // (ushort*)d_out; row n at n*2048
    const unsigned short* __restrict__ wdownb, // [1024][4096] bf16
    const float* __restrict__ b_down, const int* __restrict__ meta,
    const int* __restrict__ idx, float* __restrict__ out){
  const int lin  = blockIdx.x;                 // [0,2048)
  const int r    = lin & 7, q = lin >> 3;
  const int tile = r >> 1;
  const int xx   = (q << 1) | (r & 1);         // [0,512)
  const int p0   = xx * 32;

  const int cnt  = meta[tile];
  if (p0 >= cnt) return;
  const int off  = meta[4 + tile];

  __shared__ unsigned short smem[18432];  // As0|As1 (1024 each) | Bs0|Bs1 (8192 each)
  unsigned short* As0 = smem;
  unsigned short* As1 = smem + 1024;
  unsigned short* Bs0 = smem + 2048;
  unsigned short* Bs1 = smem + 10240;
  float* epi = (float*)smem;              // overlay: 16 rows x 260 floats = 16640B
  __shared__ int nrow[32];

  const int tid = threadIdx.x;
  if (tid < 32){
    int p = p0 + tid;
    nrow[tid] = idx[off + (p < cnt ? p : cnt - 1)];
  }
  __syncthreads();

  const int wv = tid >> 6, lane = tid & 63;
  const int wn = wv * 64;
  const int l16 = lane & 15, quad = lane >> 4;

  const int rsub = lane >> 2;
  const int kus  = (lane & 3) * 8;

  const int arow = (wv & 1)*16 + rsub;
  const unsigned short* aptr = hid + (size_t)nrow[arow] * 2048 + kus;
  const int aoff = (wv >> 1) * 32;                     // k-chunk offset
  unsigned short* asd = (wv < 2 ? As0 : As1) + ((wv & 1)*16) * 32;
  const unsigned short* bptr = wdownb + (size_t)(tile*TD + wv*64 + rsub) * DFF + tile*TU + kus;
  unsigned short* bsd0 = Bs0 + (wv*64) * 32;
  unsigned short* bsd1 = Bs1 + (wv*64) * 32;

  floatx4 acc[2][4];
  #pragma unroll
  for (int i = 0; i < 2; ++i)
    #pragma unroll
    for (int j = 0; j < 4; ++j) acc[i][j] = (floatx4){0.f,0.f,0.f,0.f};

  for (int k0 = 0; k0 < TU; k0 += 64){
    gll16(aptr + k0 + aoff, asd);
    gll16(bptr + k0,               bsd0);
    gll16(bptr + k0 + 16*DFF,      bsd0 + 16*32);
    gll16(bptr + k0 + 32*DFF,      bsd0 + 32*32);
    gll16(bptr + k0 + 48*DFF,      bsd0 + 48*32);
    gll16(bptr + k0 + 32,          bsd1);
    gll16(bptr + k0 + 32 + 16*DFF, bsd1 + 16*32);
    gll16(bptr + k0 + 32 + 32*DFF, bsd1 + 32*32);
    gll16(bptr + k0 + 32 + 48*DFF, bsd1 + 48*32);
    __syncthreads();
    {
      short8 af[2], bfr[4];
      #pragma unroll
      for (int i = 0; i < 2; ++i) af[i]  = *(const short8*)(As0 + (i*16 + l16)*32 + quad*8);
      #pragma unroll
      for (int j = 0; j < 4; ++j) bfr[j] = *(const short8*)(Bs0 + (wn + j*16 + l16)*32 + quad*8);
      #pragma unroll
      for (int i = 0; i < 2; ++i)
        #pragma unroll
        for (int j = 0; j < 4; ++j)
          acc[i][j] = __builtin_amdgcn_mfma_f32_16x16x32_bf16(af[i], bfr[j], acc[i][j], 0, 0, 0);
    }
    {
      short8 af[2], bfr[4];
      #pragma unroll
      for (int i = 0; i < 2; ++i) af[i]  = *(const short8*)(As1 + (i*16 + l16)*32 + quad*8);
      #pragma unroll
      for (int j = 0; j < 4; ++j) bfr[j] = *(const short8*)(Bs1 + (wn + j*16 + l16)*32 + quad*8);
      #pragma unroll
      for (int i = 0; i < 2; ++i)
        #pragma unroll
        for (int j = 0; j < 4; ++j)
          acc[i][j] = __builtin_amdgcn_mfma_f32_16x16x32_bf16(af[i], bfr[j], acc[i][j], 0, 0, 0);
    }
    __syncthreads();
  }

  // zero-fill non-winner 256-col blocks of OWN tokens (hid reads all drained)
  const floatx4 z4 = {0.f, 0.f, 0.f, 0.f};
  #pragma unroll
  for (int cb = 0; cb < 4; ++cb){
    if (cb == tile) continue;
    for (int c = tid; c < 32*64; c += 256){
      const int rowl = c >> 6, c4 = (c & 63) * 4;
      if (p0 + rowl < cnt)
        *(floatx4*)(out + (size_t)nrow[rowl]*DM + cb*256 + c4) = z4;
    }
  }

  // epilogue: two half-passes of 16 rows via LDS fp32 (pad stride 260), float4 stores
  #pragma unroll
  for (int half = 0; half < 2; ++half){
    #pragma unroll
    for (int j = 0; j < 4; ++j){
      const int col = wn + j*16 + l16;              // 0..255
      const float bias = b_down[tile*TD + col];
      #pragma unroll
      for (int r2 = 0; r2 < 4; ++r2){
        const int lrow = quad*4 + r2;               // 0..15
        epi[lrow*260 + col] = acc[half][j][r2] + bias;
      }
    }
    __syncthreads();
    #pragma unroll
    for (int c = tid; c < 1024; c += 256){          // 16 rows x 64 float4 chunks
      const int lrow = c >> 6, c4 = (c & 63) * 4;
      const int m = half*16 + lrow;
      if (p0 + m < cnt){
        floatx4 v = *(const floatx4*)(epi + lrow*260 + c4);
        *(floatx4*)(out + (size_t)nrow[m]*DM + tile*TD + c4) = v;
      }
    }
    __syncthreads();
  }
}

extern "C" void kernel_launch(void* const* d_in, const int* in_sizes, int n_in,
                              void* d_out, int out_size, void* d_ws, size_t ws_size,
                              hipStream_t stream){
  const float* x      = (const float*)d_in[0];
  const float* w_up   = (const float*)d_in[1];
  const float* b_up   = (const float*)d_in[2];
  const float* w_down = (const float*)d_in[3];
  const float* b_down = (const float*)d_in[4];

  // ws layout (~17.3 MB; proven layout)
  unsigned short* wupb   = (unsigned short*)d_ws;            // 4096*1024 bf16 = 8 MB
  unsigned short* wdownb = wupb + (size_t)DFF * DM;          // 1024*4096 bf16 = 8 MB
  float* partial = (float*)(wdownb + (size_t)DM * DFF);      // 262144 floats = 1 MB
  float* sig     = partial + 262144;                         // 4096 floats
  int*   ints    = (int*)(sig + 4096);
  int*   winner   = ints;                                    // 16384
  int*   idx      = ints + 16384;                            // 16384
  int*   meta     = ints + 32768;                            // [0..3]=counts [4..7]=offsets
  int*   blk_cnt  = ints + 32776;                            // [64][4]
  int*   blk_base = ints + 33032;                            // [64][4]

  float*          out  = (float*)d_out;
  float*          gate = out + (size_t)N_TOK * DM;
  unsigned short* ob16 = (unsigned short*)d_out;  // row n: hid at n*2048, xbf at n*2048+1024

  k_prep      <<<dim3(2304), 256, 0, stream>>>(w_up, w_down, partial, wupb, wdownb);
  k_sig_final <<<dim3(16),   256, 0, stream>>>(partial, sig);
  k_route     <<<dim3(N_TOK/16), 256, 0, stream>>>(x, sig, gate, winner, ob16);
  k_hist      <<<dim3(64),   256, 0, stream>>>(winner, blk_cnt);
  k_scan      <<<dim3(1),    256, 0, stream>>>(blk_cnt, meta, blk_base);
  k_scatter   <<<dim3(64),   256, 0, stream>>>(winner, blk_base, idx);
  k_gemm1     <<<dim3(4096), 256, 0, stream>>>(ob16, wupb, b_up, meta, idx, ob16);
  k_gemm2     <<<dim3(2048), 256, 0, stream>>>(ob16, wdownb, b_down, meta, idx, out);
}

// Round 10
// 257.025 us; speedup vs baseline: 1.1137x; 1.0170x over previous
//
#include <hip/hip_runtime.h>
#include <stdint.h>
#include <stddef.h>

#define N_TOK 16384
#define DM    1024
#define DFF   4096
#define NT    4
#define TU    1024   // d_ff tile
#define TD    256    // d_model tile

typedef __attribute__((ext_vector_type(8))) short  short8;
typedef __attribute__((ext_vector_type(4))) short  short4v;
typedef __attribute__((ext_vector_type(4))) float  floatx4;

__device__ inline unsigned short f2bf(float f){
  union { float f; uint32_t u; } v; v.f = f;
  uint32_t u = v.u + 0x7FFFu + ((v.u >> 16) & 1u);   // RNE
  return (unsigned short)(u >> 16);
}

// async global->LDS, 16B per lane; lds dest is wave-uniform, lane i lands at +16*i
__device__ __forceinline__ void gll16(const void* g, void* l){
  __builtin_amdgcn_global_load_lds(
      (const __attribute__((address_space(1))) unsigned int*)g,
      (__attribute__((address_space(3))) unsigned int*)l,
      16, 0, 0);
}

// ---------------- prep: sig partial sums + w_up->bf16 ----------------------
// R10: w_down conversion moved into k_route (role-split) for overlap.
__global__ void k_prep(const float* __restrict__ w_up,
                       float* __restrict__ partial,
                       unsigned short* __restrict__ wupb){
  const int tid = threadIdx.x;
  const int b = blockIdx.x;
  const int tile = b >> 6, chunk = b & 63;
  const int c0 = tid * 4;
  const int row0 = tile*TU + chunk*16;
  float s0=0.f, s1=0.f, s2=0.f, s3=0.f;
  const float* base = w_up + (size_t)row0 * DM + c0;
  #pragma unroll
  for (int r = 0; r < 16; ++r){
    floatx4 v = *(const floatx4*)(base + (size_t)r * DM);
    s0 += v[0]; s1 += v[1]; s2 += v[2]; s3 += v[3];
    short4v p;
    p[0]=(short)f2bf(v[0]); p[1]=(short)f2bf(v[1]);
    p[2]=(short)f2bf(v[2]); p[3]=(short)f2bf(v[3]);
    *(short4v*)(wupb + (size_t)(row0 + r) * DM + c0) = p;
  }
  float* p = partial + ((size_t)tile*DM + c0) * 64 + chunk;
  p[0] = s0; p[64] = s1; p[128] = s2; p[192] = s3;
}

// ---------------- sig finalize ----------------------------------------------
__global__ void k_sig_final(const float* __restrict__ partial,
                            float* __restrict__ sig){
  const int g = blockIdx.x * 256 + threadIdx.x;   // 0..4095 = tile*1024+col
  const float* p = partial + (size_t)g * 64;
  float s = 0.f;
  #pragma unroll
  for (int i = 0; i < 64; ++i) s += p[i];
  sig[g] = (s > 0.f) ? 1.f : ((s < 0.f) ? -1.f : 0.f);
}

// ---------------- routing (+ fused w_down->bf16 conversion) ------------------
// R10: blocks [0,1024) = routing (16 tokens/block, 4/wave); blocks
// [1024,3072) = w_down bf16 conversion. The pure-memory conv stream
// co-schedules with route's fp64-VALU work (m114 overlap) and saves a
// launch. fp64 sum order UNCHANGED -> winner bit-identical. wdownb is
// consumed only by gemm2 (far downstream).
// xbf row n lives in SECOND 2048B of out row n (ushort offset n*2048+1024).
__global__ __launch_bounds__(256) void k_route(
    const float* __restrict__ x, const float* __restrict__ sig,
    const float* __restrict__ w_down, unsigned short* __restrict__ wdownb,
    float* __restrict__ gate_out, int* __restrict__ winner,
    unsigned short* __restrict__ xbf){
  const int tid = threadIdx.x;
  if (blockIdx.x >= 1024){
    const size_t i = ((size_t)(blockIdx.x - 1024) * 256 + tid) * 8;
    floatx4 v0 = *(const floatx4*)(w_down + i);
    floatx4 v1 = *(const floatx4*)(w_down + i + 4);
    short8 p;
    p[0]=(short)f2bf(v0[0]); p[1]=(short)f2bf(v0[1]); p[2]=(short)f2bf(v0[2]); p[3]=(short)f2bf(v0[3]);
    p[4]=(short)f2bf(v1[0]); p[5]=(short)f2bf(v1[1]); p[6]=(short)f2bf(v1[2]); p[7]=(short)f2bf(v1[3]);
    *(short8*)(wdownb + i) = p;
    return;
  }
  __shared__ float ssig[NT * DM];
  for (int i = tid; i < NT*DM; i += 256) ssig[i] = sig[i];
  __syncthreads();
  const int wv = tid >> 6, lane = tid & 63;

  floatx4 sg[4][4];
  #pragma unroll
  for (int j = 0; j < 4; ++j){
    const int c = j*256 + lane*4;
    #pragma unroll
    for (int tt = 0; tt < 4; ++tt)
      sg[j][tt] = *(const floatx4*)(ssig + tt*DM + c);
  }

  #pragma unroll
  for (int t = 0; t < 4; ++t){
    const int n = blockIdx.x * 16 + wv * 4 + t;
    const float* xr = x + (size_t)n * DM;
    unsigned short* xb = xbf + (size_t)n * 2048 + 1024;
    double a0=0.0, a1=0.0, a2=0.0, a3=0.0;
    #pragma unroll
    for (int j = 0; j < 4; ++j){
      const int c = j*256 + lane*4;
      floatx4 v = *(const floatx4*)(xr + c);
      short4v p;
      p[0]=(short)f2bf(v[0]); p[1]=(short)f2bf(v[1]);
      p[2]=(short)f2bf(v[2]); p[3]=(short)f2bf(v[3]);
      *(short4v*)(xb + c) = p;
      #pragma unroll
      for (int u = 0; u < 4; ++u){
        double xv = (double)v[u];
        a0 += xv * (double)sg[j][0][u];
        a1 += xv * (double)sg[j][1][u];
        a2 += xv * (double)sg[j][2][u];
        a3 += xv * (double)sg[j][3][u];
      }
    }
    #pragma unroll
    for (int off = 32; off > 0; off >>= 1){
      a0 += __shfl_down(a0, off, 64);
      a1 += __shfl_down(a1, off, 64);
      a2 += __shfl_down(a2, off, 64);
      a3 += __shfl_down(a3, off, 64);
    }
    if (lane == 0){
      double s[4] = {a0, a1, a2, a3};
      int w = 0;
      #pragma unroll
      for (int tt = 1; tt < 4; ++tt) if (s[tt] > s[w]) w = tt;   // first-max tiebreak
      floatx4 g = { w==0 ? 1.f:0.f, w==1 ? 1.f:0.f, w==2 ? 1.f:0.f, w==3 ? 1.f:0.f };
      *(floatx4*)(gate_out + (size_t)n * 4) = g;
      winner[n] = w;
    }
  }
}

// ---------------- histogram / scan / scatter (atomic-free, deterministic) ---
__global__ void k_hist(const int* __restrict__ winner,
                       int* __restrict__ blk_cnt){   // [64][4]
  __shared__ int wcnt[4][NT];
  const int tid = threadIdx.x, wv = tid >> 6, lane = tid & 63;
  const int w = winner[blockIdx.x * 256 + tid];
  #pragma unroll
  for (int t = 0; t < NT; ++t){
    unsigned long long m = __ballot(w == t);
    if (lane == 0) wcnt[wv][t] = __popcll(m);
  }
  __syncthreads();
  if (tid < NT){
    int s = wcnt[0][tid] + wcnt[1][tid] + wcnt[2][tid] + wcnt[3][tid];
    blk_cnt[blockIdx.x * NT + tid] = s;
  }
}

__global__ void k_scan(const int* __restrict__ blk_cnt,
                       int* __restrict__ meta, int* __restrict__ blk_base){
  __shared__ int s[256];
  const int tid = threadIdx.x;
  s[tid] = blk_cnt[tid];                    // one coalesced load
  __syncthreads();
  if (tid == 0){
    int tot[NT] = {0,0,0,0};
    for (int b = 0; b < 64; ++b)
      for (int t = 0; t < NT; ++t) tot[t] += s[b*NT + t];
    int off = 0, base[NT];
    for (int t = 0; t < NT; ++t){ meta[t] = tot[t]; meta[4+t] = off; base[t] = off; off += tot[t]; }
    for (int b = 0; b < 64; ++b)
      for (int t = 0; t < NT; ++t){ int c = s[b*NT + t]; s[b*NT + t] = base[t]; base[t] += c; }
  }
  __syncthreads();
  blk_base[tid] = s[tid];                   // parallel store
}

__global__ void k_scatter(const int* __restrict__ winner,
                          const int* __restrict__ blk_base,
                          int* __restrict__ idx){
  __shared__ int wcnt[4][NT];
  const int tid = threadIdx.x, wv = tid >> 6, lane = tid & 63;
  const int n = blockIdx.x * 256 + tid;
  const int w = winner[n];
  unsigned long long mymask = 0;
  #pragma unroll
  for (int t = 0; t < NT; ++t){
    unsigned long long m = __ballot(w == t);
    if (lane == 0) wcnt[wv][t] = __popcll(m);
    if (t == w) mymask = m;
  }
  __syncthreads();
  const unsigned long long below = (lane == 0) ? 0ull : (~0ull >> (64 - lane));
  int pos = blk_base[blockIdx.x * NT + w] + __popcll(mymask & below);
  for (int v = 0; v < wv; ++v) pos += wcnt[v][w];
  idx[pos] = n;
}

// ---------------- GEMM1: hid = relu(xbf[rows] @ wupb[tile]^T + b_up) --------
// BM=128 BN=128; proven 2-barrier K-loop (pipeline variants R1-R3 all lost).
// Tile-into-residue XCD swizzle (R8, validated: FETCH 55->27MB).
// R10: LDS shaved to EXACTLY 32,768B. Occupancy scaled 1/LDS all session
// (66KB->11.8%, 49KB->16.7%, 33.3KB->24.3%): residency is LDS-quantized
// blocks/CU. The old separate nrow[128] (+512B) pushed the block over the
// 32KB boundary (160/33.3=4 blocks/CU; 160/32=5). Fix: nrow staged through
// smem in a prologue; A-pointers + epilogue row-ids/valids hoisted to
// registers (static-indexed per rule #20); K-loop then reuses all 32KB.
__global__ __launch_bounds__(256, 2) void k_gemm1(
    const unsigned short* __restrict__ xbf,   // (ushort*)d_out; row n at n*2048+1024
    const unsigned short* __restrict__ wupb,  // [4096][1024] bf16
    const float* __restrict__ b_up, const int* __restrict__ meta,
    const int* __restrict__ idx, unsigned short* __restrict__ hid){
  // XCD swizzle: r=lin&7 -> (tile, chunk parity); q=lin>>3 -> (nb, chunk half)
  const int lin  = blockIdx.x;                 // [0,4096)
  const int r    = lin & 7, q = lin >> 3;
  const int tile = r >> 1;
  const int nb   = q & 7;
  const int chunk = ((q >> 3) << 1) | (r & 1); // [0,128)
  const int p0   = chunk * 128;

  const int cnt  = meta[tile];
  if (p0 >= cnt) return;
  const int off  = meta[4 + tile];

  __shared__ unsigned short smem[16384];  // 32768B exactly: As0|As1|Bs0|Bs1; prologue nrow + epi overlay
  unsigned short* As0 = smem;
  unsigned short* As1 = smem + 4096;
  unsigned short* Bs0 = smem + 8192;
  unsigned short* Bs1 = smem + 12288;

  const int tid = threadIdx.x;
  const int wv = tid >> 6, lane = tid & 63;
  const int wm = (wv >> 1) * 64, wn = (wv & 1) * 64;
  const int l16 = lane & 15, quad = lane >> 4;
  const int rsub = lane >> 2;          // 0..15
  const int kus  = (lane & 3) * 8;     // ushort offset within 32-elem row

  // ---- prologue: nrow via smem, consumed into registers, then smem is freed
  int* nrs = (int*)smem;               // first 512B, transient
  if (tid < 128){
    int p = p0 + tid;
    nrs[tid] = idx[off + (p < cnt ? p : cnt - 1)];
  }
  __syncthreads();
  const int ra = wv*32 + rsub;
  const unsigned short* aptr0 = xbf + (size_t)nrs[ra]      * 2048 + 1024 + kus;
  const unsigned short* aptr1 = xbf + (size_t)nrs[ra + 16] * 2048 + 1024 + kus;
  int  enr[2][4];                      // epilogue token rows (static-indexed)
  bool ev [2][4];                      // epilogue valid bits
  #pragma unroll
  for (int half = 0; half < 2; ++half){
    #pragma unroll
    for (int s = 0; s < 4; ++s){
      const int lrow = (tid + s*256) >> 4;      // 0..63
      const int m = half*64 + lrow;
      ev [half][s] = (p0 + m < cnt);
      enr[half][s] = nrs[m];
    }
  }
  __syncthreads();                     // all nrs reads done before K-loop overwrites

  const unsigned short* bptr0 = wupb + (size_t)(tile*TU + nb*128 + wv*32 + rsub) * DM + kus;
  const unsigned short* bptr1 = bptr0 + 16 * DM;

  // wave-uniform LDS dests ([row][32] layout, 64B row stride)
  unsigned short* a0d0 = As0 + (wv*32) * 32;  unsigned short* a0d1 = a0d0 + 16*32;
  unsigned short* a1d0 = As1 + (wv*32) * 32;  unsigned short* a1d1 = a1d0 + 16*32;
  unsigned short* b0d0 = Bs0 + (wv*32) * 32;  unsigned short* b0d1 = b0d0 + 16*32;
  unsigned short* b1d0 = Bs1 + (wv*32) * 32;  unsigned short* b1d1 = b1d0 + 16*32;

  floatx4 acc[4][4];
  #pragma unroll
  for (int i = 0; i < 4; ++i)
    #pragma unroll
    for (int j = 0; j < 4; ++j) acc[i][j] = (floatx4){0.f,0.f,0.f,0.f};

  for (int k0 = 0; k0 < DM; k0 += 64){
    gll16(aptr0 + k0,      a0d0);
    gll16(aptr1 + k0,      a0d1);
    gll16(aptr0 + k0 + 32, a1d0);
    gll16(aptr1 + k0 + 32, a1d1);
    gll16(bptr0 + k0,      b0d0);
    gll16(bptr1 + k0,      b0d1);
    gll16(bptr0 + k0 + 32, b1d0);
    gll16(bptr1 + k0 + 32, b1d1);
    __syncthreads();
    {
      short8 af[4], bfr[4];
      #pragma unroll
      for (int i = 0; i < 4; ++i) af[i]  = *(const short8*)(As0 + (wm + i*16 + l16)*32 + quad*8);
      #pragma unroll
      for (int j = 0; j < 4; ++j) bfr[j] = *(const short8*)(Bs0 + (wn + j*16 + l16)*32 + quad*8);
      #pragma unroll
      for (int i = 0; i < 4; ++i)
        #pragma unroll
        for (int j = 0; j < 4; ++j)
          acc[i][j] = __builtin_amdgcn_mfma_f32_16x16x32_bf16(af[i], bfr[j], acc[i][j], 0, 0, 0);
    }
    {
      short8 af[4], bfr[4];
      #pragma unroll
      for (int i = 0; i < 4; ++i) af[i]  = *(const short8*)(As1 + (wm + i*16 + l16)*32 + quad*8);
      #pragma unroll
      for (int j = 0; j < 4; ++j) bfr[j] = *(const short8*)(Bs1 + (wn + j*16 + l16)*32 + quad*8);
      #pragma unroll
      for (int i = 0; i < 4; ++i)
        #pragma unroll
        for (int j = 0; j < 4; ++j)
          acc[i][j] = __builtin_amdgcn_mfma_f32_16x16x32_bf16(af[i], bfr[j], acc[i][j], 0, 0, 0);
    }
    __syncthreads();
  }

  // epilogue: two half-passes of 64 rows through LDS (pad stride 136), wide stores
  const int gcol0 = nb*128;
  #pragma unroll
  for (int half = 0; half < 2; ++half){
    if ((wv >> 1) == half){
      #pragma unroll
      for (int i = 0; i < 4; ++i){
        #pragma unroll
        for (int j = 0; j < 4; ++j){
          const int col = wn + j*16 + l16;          // 0..127
          const float bias = b_up[tile*TU + gcol0 + col];
          #pragma unroll
          for (int r2 = 0; r2 < 4; ++r2){
            const int lrow = i*16 + quad*4 + r2;    // 0..63
            float v = acc[i][j][r2] + bias;
            smem[lrow*136 + col] = f2bf(v > 0.f ? v : 0.f);
          }
        }
      }
    }
    __syncthreads();
    // 64 rows x 16 chunks of 8 ushorts (128 cols); row ids from registers
    #pragma unroll
    for (int s = 0; s < 4; ++s){
      const int c = tid + s*256;
      const int lrow = c >> 4, k8 = (c & 15) * 8;
      if (ev[half][s]){
        short8 vv = *(const short8*)(smem + lrow*136 + k8);
        *(short8*)(hid + (size_t)enr[half][s]*2048 + gcol0 + k8) = vv;
      }
    }
    __syncthreads();
  }
}

// ---------------- GEMM2: out = hid @ wdownb[tile]^T + b_down + zero-fill ----
// BM=32 BN=256, BK=64 paired buffers (R0 structure verbatim). Tile-into-
// residue XCD swizzle (id%8 = 2*tile + (x&1)): each XCD serves one tile ->
// 512KB B panel L2-resident. Zero-fill fused after K-loop's final barrier.
__global__ __launch_bounds__(256, 2) void k_gemm2(
    const unsigned short* __restrict__ hid,    // (ushort*)d_out; row n at n*2048
    const unsigned short* __restrict__ wdownb, // [1024][4096] bf16
    const float* __restrict__ b_down, const int* __restrict__ meta,
    const int* __restrict__ idx, float* __restrict__ out){
  const int lin  = blockIdx.x;                 // [0,2048)
  const int r    = lin & 7, q = lin >> 3;
  const int tile = r >> 1;
  const int xx   = (q << 1) | (r & 1);         // [0,512)
  const int p0   = xx * 32;

  const int cnt  = meta[tile];
  if (p0 >= cnt) return;
  const int off  = meta[4 + tile];

  __shared__ unsigned short smem[18432];  // As0|As1 (1024 each) | Bs0|Bs1 (8192 each)
  unsigned short* As0 = smem;
  unsigned short* As1 = smem + 1024;
  unsigned short* Bs0 = smem + 2048;
  unsigned short* Bs1 = smem + 10240;
  float* epi = (float*)smem;              // overlay: 16 rows x 260 floats = 16640B
  __shared__ int nrow[32];

  const int tid = threadIdx.x;
  if (tid < 32){
    int p = p0 + tid;
    nrow[tid] = idx[off + (p < cnt ? p : cnt - 1)];
  }
  __syncthreads();

  const int wv = tid >> 6, lane = tid & 63;
  const int wn = wv * 64;
  const int l16 = lane & 15, quad = lane >> 4;

  const int rsub = lane >> 2;
  const int kus  = (lane & 3) * 8;

  const int arow = (wv & 1)*16 + rsub;
  const unsigned short* aptr = hid + (size_t)nrow[arow] * 2048 + kus;
  const int aoff = (wv >> 1) * 32;                     // k-chunk offset
  unsigned short* asd = (wv < 2 ? As0 : As1) + ((wv & 1)*16) * 32;
  const unsigned short* bptr = wdownb + (size_t)(tile*TD + wv*64 + rsub) * DFF + tile*TU + kus;
  unsigned short* bsd0 = Bs0 + (wv*64) * 32;
  unsigned short* bsd1 = Bs1 + (wv*64) * 32;

  floatx4 acc[2][4];
  #pragma unroll
  for (int i = 0; i < 2; ++i)
    #pragma unroll
    for (int j = 0; j < 4; ++j) acc[i][j] = (floatx4){0.f,0.f,0.f,0.f};

  for (int k0 = 0; k0 < TU; k0 += 64){
    gll16(aptr + k0 + aoff, asd);
    gll16(bptr + k0,               bsd0);
    gll16(bptr + k0 + 16*DFF,      bsd0 + 16*32);
    gll16(bptr + k0 + 32*DFF,      bsd0 + 32*32);
    gll16(bptr + k0 + 48*DFF,      bsd0 + 48*32);
    gll16(bptr + k0 + 32,          bsd1);
    gll16(bptr + k0 + 32 + 16*DFF, bsd1 + 16*32);
    gll16(bptr + k0 + 32 + 32*DFF, bsd1 + 32*32);
    gll16(bptr + k0 + 32 + 48*DFF, bsd1 + 48*32);
    __syncthreads();
    {
      short8 af[2], bfr[4];
      #pragma unroll
      for (int i = 0; i < 2; ++i) af[i]  = *(const short8*)(As0 + (i*16 + l16)*32 + quad*8);
      #pragma unroll
      for (int j = 0; j < 4; ++j) bfr[j] = *(const short8*)(Bs0 + (wn + j*16 + l16)*32 + quad*8);
      #pragma unroll
      for (int i = 0; i < 2; ++i)
        #pragma unroll
        for (int j = 0; j < 4; ++j)
          acc[i][j] = __builtin_amdgcn_mfma_f32_16x16x32_bf16(af[i], bfr[j], acc[i][j], 0, 0, 0);
    }
    {
      short8 af[2], bfr[4];
      #pragma unroll
      for (int i = 0; i < 2; ++i) af[i]  = *(const short8*)(As1 + (i*16 + l16)*32 + quad*8);
      #pragma unroll
      for (int j = 0; j < 4; ++j) bfr[j] = *(const short8*)(Bs1 + (wn + j*16 + l16)*32 + quad*8);
      #pragma unroll
      for (int i = 0; i < 2; ++i)
        #pragma unroll
        for (int j = 0; j < 4; ++j)
          acc[i][j] = __builtin_amdgcn_mfma_f32_16x16x32_bf16(af[i], bfr[j], acc[i][j], 0, 0, 0);
    }
    __syncthreads();
  }

  // zero-fill non-winner 256-col blocks of OWN tokens (hid reads all drained)
  const floatx4 z4 = {0.f, 0.f, 0.f, 0.f};
  #pragma unroll
  for (int cb = 0; cb < 4; ++cb){
    if (cb == tile) continue;
    for (int c = tid; c < 32*64; c += 256){
      const int rowl = c >> 6, c4 = (c & 63) * 4;
      if (p0 + rowl < cnt)
        *(floatx4*)(out + (size_t)nrow[rowl]*DM + cb*256 + c4) = z4;
    }
  }

  // epilogue: two half-passes of 16 rows via LDS fp32 (pad stride 260), float4 stores
  #pragma unroll
  for (int half = 0; half < 2; ++half){
    #pragma unroll
    for (int j = 0; j < 4; ++j){
      const int col = wn + j*16 + l16;              // 0..255
      const float bias = b_down[tile*TD + col];
      #pragma unroll
      for (int r2 = 0; r2 < 4; ++r2){
        const int lrow = quad*4 + r2;               // 0..15
        epi[lrow*260 + col] = acc[half][j][r2] + bias;
      }
    }
    __syncthreads();
    #pragma unroll
    for (int c = tid; c < 1024; c += 256){          // 16 rows x 64 float4 chunks
      const int lrow = c >> 6, c4 = (c & 63) * 4;
      const int m = half*16 + lrow;
      if (p0 + m < cnt){
        floatx4 v = *(const floatx4*)(epi + lrow*260 + c4);
        *(floatx4*)(out + (size_t)nrow[m]*DM + tile*TD + c4) = v;
      }
    }
    __syncthreads();
  }
}

extern "C" void kernel_launch(void* const* d_in, const int* in_sizes, int n_in,
                              void* d_out, int out_size, void* d_ws, size_t ws_size,
                              hipStream_t stream){
  const float* x      = (const float*)d_in[0];
  const float* w_up   = (const float*)d_in[1];
  const float* b_up   = (const float*)d_in[2];
  const float* w_down = (const float*)d_in[3];
  const float* b_down = (const float*)d_in[4];

  // ws layout (~17.3 MB; proven layout)
  unsigned short* wupb   = (unsigned short*)d_ws;            // 4096*1024 bf16 = 8 MB
  unsigned short* wdownb = wupb + (size_t)DFF * DM;          // 1024*4096 bf16 = 8 MB
  float* partial = (float*)(wdownb + (size_t)DM * DFF);      // 262144 floats = 1 MB
  float* sig     = partial + 262144;                         // 4096 floats
  int*   ints    = (int*)(sig + 4096);
  int*   winner   = ints;                                    // 16384
  int*   idx      = ints + 16384;                            // 16384
  int*   meta     = ints + 32768;                            // [0..3]=counts [4..7]=offsets
  int*   blk_cnt  = ints + 32776;                            // [64][4]
  int*   blk_base = ints + 33032;                            // [64][4]

  float*          out  = (float*)d_out;
  float*          gate = out + (size_t)N_TOK * DM;
  unsigned short* ob16 = (unsigned short*)d_out;  // row n: hid at n*2048, xbf at n*2048+1024

  k_prep      <<<dim3(256),  256, 0, stream>>>(w_up, partial, wupb);
  k_sig_final <<<dim3(16),   256, 0, stream>>>(partial, sig);
  k_route     <<<dim3(3072), 256, 0, stream>>>(x, sig, w_down, wdownb, gate, winner, ob16);
  k_hist      <<<dim3(64),   256, 0, stream>>>(winner, blk_cnt);
  k_scan      <<<dim3(1),    256, 0, stream>>>(blk_cnt, meta, blk_base);
  k_scatter   <<<dim3(64),   256, 0, stream>>>(winner, blk_base, idx);
  k_gemm1     <<<dim3(4096), 256, 0, stream>>>(ob16, wupb, b_up, meta, idx, ob16);
  k_gemm2     <<<dim3(2048), 256, 0, stream>>>(ob16, wdownb, b_down, meta, idx, out);
}